// Round 11
// baseline (158.195 us; speedup 1.0000x reference)
//
#include <hip/hip_runtime.h>
#include <math.h>

namespace {

constexpr int Bsz   = 16384;
constexpr int T     = 200;
constexpr int F     = 4;
constexpr int H     = 10;
constexpr int HP    = 16;   // FC LDS padding: 16 slots/step
constexpr int BLOCK = 64;

// tanh(x) = 1 - 2/(exp(2x)+1); saturates correctly to +/-1 for |x| large.
__device__ __forceinline__ float fast_tanh(float x) {
  float e = exp2f(x * 2.8853900817779268f);   // exp(2x) via v_exp_f32
  return 1.0f - 2.0f * __builtin_amdgcn_rcpf(e + 1.0f);
}

__device__ __forceinline__ float fast_sigmoid(float x) {
  float e = exp2f(x * -1.4426950408889634f);  // exp(-x)
  return __builtin_amdgcn_rcpf(1.0f + e);
}

// Broadcast sub-lane J's value to all lanes of each 8-lane group.
// ds_swizzle BitMode: new_lane = (lane & 0x18) | J.
template <int J>
__device__ __forceinline__ float bcast8(float v) {
  return __int_as_float(
      __builtin_amdgcn_ds_swizzle(__float_as_int(v), (J << 5) | 0x18));
}

#define PIN(v) asm volatile("" : "+v"(v))

// launch_bounds(64,1): the ONLY config the allocator has ever granted >90
// arch VGPRs (r3: 204). min-waves=2 variants (r10) granted 68 and spilled
// 4 regs/thread (WRITE_SIZE showed exactly 2 MB of scratch stores).
// Structure: 8-lane group handles TWO batch elements with interleaved
// dependency chains — element b's FMAs hide element a's tanh/ds_swizzle
// latency (r10's floor was ~708 cyc/wave-step of serial chain vs ~230 of
// issue; lanes are lockstep so only in-stream ILP can fill the gap).
__global__ __launch_bounds__(BLOCK, 1) void rnn2_oct_x2(
    const float* __restrict__ x,
    const float* __restrict__ W_ih0, const float* __restrict__ W_hh0,
    const float* __restrict__ b_ih0, const float* __restrict__ b_hh0,
    const float* __restrict__ W_ih1, const float* __restrict__ W_hh1,
    const float* __restrict__ b_ih1, const float* __restrict__ b_hh1,
    const float* __restrict__ W_fc, const float* __restrict__ b_fc,
    float* __restrict__ out) {
  // FC weights in LDS, padded to HP floats per timestep (pad = 0).
  __shared__ float s_wfc[T * HP];
  for (int i = threadIdx.x; i < T * HP; i += BLOCK) {
    int t = i >> 4, u = i & 15;
    s_wfc[i] = (u < H) ? W_fc[t * H + u] : 0.0f;
  }
  __syncthreads();

  const int lane = threadIdx.x;
  const int grp  = lane >> 3;              // 8-lane group id within the wave
  const int r    = lane & 7;               // sub-lane in group
  const int ea   = blockIdx.x * 16 + grp * 2;  // element a
  const int eb   = ea + 1;                     // element b
  const int uU = r;                        // first unit  (always real)
  const int uV = 8 + r;                    // second unit (real only r < 2)
  const bool vV = (uV < H);

  // ---- units' weights (shared by both elements), pinned (76 floats) ----
  float wi0U[F], wh0U[H], wi1U[H], wh1U[H];
  float wi0V[F], wh0V[H], wi1V[H], wh1V[H];
  float bU0, bU1, bV0, bV1;
#pragma unroll
  for (int j = 0; j < F; ++j) {
    wi0U[j] = W_ih0[uU * F + j];              PIN(wi0U[j]);
    wi0V[j] = vV ? W_ih0[uV * F + j] : 0.0f;  PIN(wi0V[j]);
  }
#pragma unroll
  for (int j = 0; j < H; ++j) {
    wh0U[j] = W_hh0[uU * H + j];              PIN(wh0U[j]);
    wh0V[j] = vV ? W_hh0[uV * H + j] : 0.0f;  PIN(wh0V[j]);
    wi1U[j] = W_ih1[uU * H + j];              PIN(wi1U[j]);
    wi1V[j] = vV ? W_ih1[uV * H + j] : 0.0f;  PIN(wi1V[j]);
    wh1U[j] = W_hh1[uU * H + j];              PIN(wh1U[j]);
    wh1V[j] = vV ? W_hh1[uV * H + j] : 0.0f;  PIN(wh1V[j]);
  }
  bU0 = b_ih0[uU] + b_hh0[uU];               PIN(bU0);
  bV0 = vV ? (b_ih0[uV] + b_hh0[uV]) : 0.0f; PIN(bV0);
  bU1 = b_ih1[uU] + b_hh1[uU];               PIN(bU1);
  bV1 = vV ? (b_ih1[uV] + b_hh1[uV]) : 0.0f; PIN(bV1);

  const float4* __restrict__ xra =
      reinterpret_cast<const float4*>(x + (size_t)ea * (T * F));
  const float4* __restrict__ xrb =
      reinterpret_cast<const float4*>(x + (size_t)eb * (T * F));

  float h0a[H], h1a[H], h0b[H], h1b[H];
#pragma unroll
  for (int j = 0; j < H; ++j) { h0a[j] = h1a[j] = h0b[j] = h1b[j] = 0.0f; }
  float acca = 0.0f, accb = 0.0f;

  float4 xa = xra[0], xb = xrb[0];
#pragma unroll 1
  for (int t = 0; t < T; ++t) {
    float4 xna = (t + 1 < T) ? xra[t + 1] : xa;   // software prefetch
    float4 xnb = (t + 1 < T) ? xrb[t + 1] : xb;

    // FC weights for this step (shared by both elements).
    float fU = s_wfc[t * HP + uU];
    float fV = s_wfc[t * HP + uV];

    // ---- layer 0, both elements interleaved (4 independent chains) ----
    float sUa = bU0, sVa = bV0, sUb = bU0, sVb = bV0;
    sUa = fmaf(wi0U[0], xa.x, sUa);  sUb = fmaf(wi0U[0], xb.x, sUb);
    sVa = fmaf(wi0V[0], xa.x, sVa);  sVb = fmaf(wi0V[0], xb.x, sVb);
    sUa = fmaf(wi0U[1], xa.y, sUa);  sUb = fmaf(wi0U[1], xb.y, sUb);
    sVa = fmaf(wi0V[1], xa.y, sVa);  sVb = fmaf(wi0V[1], xb.y, sVb);
    sUa = fmaf(wi0U[2], xa.z, sUa);  sUb = fmaf(wi0U[2], xb.z, sUb);
    sVa = fmaf(wi0V[2], xa.z, sVa);  sVb = fmaf(wi0V[2], xb.z, sVb);
    sUa = fmaf(wi0U[3], xa.w, sUa);  sUb = fmaf(wi0U[3], xb.w, sUb);
    sVa = fmaf(wi0V[3], xa.w, sVa);  sVb = fmaf(wi0V[3], xb.w, sVb);
#pragma unroll
    for (int j = 0; j < H; ++j) {
      sUa = fmaf(wh0U[j], h0a[j], sUa);  sUb = fmaf(wh0U[j], h0b[j], sUb);
      sVa = fmaf(wh0V[j], h0a[j], sVa);  sVb = fmaf(wh0V[j], h0b[j], sVb);
    }
    float mUa = fast_tanh(sUa), mVa = fast_tanh(sVa);
    float mUb = fast_tanh(sUb), mVb = fast_tanh(sVb);

    // issue h0 exchanges for BOTH elements (DS pipe), then cover their
    // latency with the h1-recurrent halves (40 independent FMAs).
    h0a[0] = bcast8<0>(mUa); h0a[1] = bcast8<1>(mUa);
    h0a[2] = bcast8<2>(mUa); h0a[3] = bcast8<3>(mUa);
    h0a[4] = bcast8<4>(mUa); h0a[5] = bcast8<5>(mUa);
    h0a[6] = bcast8<6>(mUa); h0a[7] = bcast8<7>(mUa);
    h0a[8] = bcast8<0>(mVa); h0a[9] = bcast8<1>(mVa);
    h0b[0] = bcast8<0>(mUb); h0b[1] = bcast8<1>(mUb);
    h0b[2] = bcast8<2>(mUb); h0b[3] = bcast8<3>(mUb);
    h0b[4] = bcast8<4>(mUb); h0b[5] = bcast8<5>(mUb);
    h0b[6] = bcast8<6>(mUb); h0b[7] = bcast8<7>(mUb);
    h0b[8] = bcast8<0>(mVb); h0b[9] = bcast8<1>(mVb);

    float pUa = bU1, pVa = bV1, pUb = bU1, pVb = bV1;
#pragma unroll
    for (int j = 0; j < H; ++j) {
      pUa = fmaf(wh1U[j], h1a[j], pUa);  pUb = fmaf(wh1U[j], h1b[j], pUb);
      pVa = fmaf(wh1V[j], h1a[j], pVa);  pVb = fmaf(wh1V[j], h1b[j], pVb);
    }

    // ---- layer 1, h0-dependent halves ----
#pragma unroll
    for (int j = 0; j < H; ++j) {
      pUa = fmaf(wi1U[j], h0a[j], pUa);  pUb = fmaf(wi1U[j], h0b[j], pUb);
      pVa = fmaf(wi1V[j], h0a[j], pVa);  pVb = fmaf(wi1V[j], h0b[j], pVb);
    }
    mUa = fast_tanh(pUa); mVa = fast_tanh(pVa);
    mUb = fast_tanh(pUb); mVb = fast_tanh(pVb);

    // FC head contributions (pad units read 0 weights from LDS)
    acca = fmaf(mUa, fU, acca);  accb = fmaf(mUb, fU, accb);
    acca = fmaf(mVa, fV, acca);  accb = fmaf(mVb, fV, accb);

    // h1 exchanges for both elements
    h1a[0] = bcast8<0>(mUa); h1a[1] = bcast8<1>(mUa);
    h1a[2] = bcast8<2>(mUa); h1a[3] = bcast8<3>(mUa);
    h1a[4] = bcast8<4>(mUa); h1a[5] = bcast8<5>(mUa);
    h1a[6] = bcast8<6>(mUa); h1a[7] = bcast8<7>(mUa);
    h1a[8] = bcast8<0>(mVa); h1a[9] = bcast8<1>(mVa);
    h1b[0] = bcast8<0>(mUb); h1b[1] = bcast8<1>(mUb);
    h1b[2] = bcast8<2>(mUb); h1b[3] = bcast8<3>(mUb);
    h1b[4] = bcast8<4>(mUb); h1b[5] = bcast8<5>(mUb);
    h1b[6] = bcast8<6>(mUb); h1b[7] = bcast8<7>(mUb);
    h1b[8] = bcast8<0>(mVb); h1b[9] = bcast8<1>(mVb);

    xa = xna; xb = xnb;
  }

  // 8-lane reduce of both FC accumulators
  acca += __shfl_xor(acca, 1);  accb += __shfl_xor(accb, 1);
  acca += __shfl_xor(acca, 2);  accb += __shfl_xor(accb, 2);
  acca += __shfl_xor(acca, 4);  accb += __shfl_xor(accb, 4);
  if (r == 0) {
    out[ea] = fast_sigmoid(acca + b_fc[0]);
    out[eb] = fast_sigmoid(accb + b_fc[0]);
  }
}

}  // namespace

extern "C" void kernel_launch(void* const* d_in, const int* in_sizes, int n_in,
                              void* d_out, int out_size, void* d_ws, size_t ws_size,
                              hipStream_t stream) {
  const float* x     = (const float*)d_in[0];
  const float* W_ih0 = (const float*)d_in[1];
  const float* W_hh0 = (const float*)d_in[2];
  const float* b_ih0 = (const float*)d_in[3];
  const float* b_hh0 = (const float*)d_in[4];
  const float* W_ih1 = (const float*)d_in[5];
  const float* W_hh1 = (const float*)d_in[6];
  const float* b_ih1 = (const float*)d_in[7];
  const float* b_hh1 = (const float*)d_in[8];
  const float* W_fc  = (const float*)d_in[9];
  const float* b_fc  = (const float*)d_in[10];
  float* out = (float*)d_out;

  dim3 grid(Bsz / 16), block(BLOCK);
  hipLaunchKernelGGL(rnn2_oct_x2, grid, block, 0, stream,
                     x, W_ih0, W_hh0, b_ih0, b_hh0,
                     W_ih1, W_hh1, b_ih1, b_hh1, W_fc, b_fc, out);
}

// Round 12
// 112.359 us; speedup vs baseline: 1.4079x; 1.4079x over previous
//
#include <hip/hip_runtime.h>
#include <hip/hip_fp16.h>
#include <math.h>
#include <stdint.h>

namespace {

constexpr int Bsz   = 16384;
constexpr int T     = 200;
constexpr int F     = 4;
constexpr int H     = 10;
constexpr int HP    = 16;
constexpr int BLOCK = 64;

typedef float    f32x4 __attribute__((ext_vector_type(4)));
typedef uint32_t u32x4 __attribute__((ext_vector_type(4)));
typedef __fp16   f16x8 __attribute__((ext_vector_type(8)));

// tanh(x) = 1 - 2/(exp(2x)+1); saturates correctly to +/-1 for |x| large.
__device__ __forceinline__ float fast_tanh(float x) {
  float e = exp2f(x * 2.8853900817779268f);
  return 1.0f - 2.0f * __builtin_amdgcn_rcpf(e + 1.0f);
}

__device__ __forceinline__ float fast_sigmoid(float x) {
  float e = exp2f(x * -1.4426950408889634f);
  return __builtin_amdgcn_rcpf(1.0f + e);
}

// lane ^= 16 within each 32-lane half (ds_swizzle BitMode xor=16): 0x401F
__device__ __forceinline__ uint32_t swz16(uint32_t v) {
  return (uint32_t)__builtin_amdgcn_ds_swizzle((int)v, 0x401F);
}

// pack two f32 -> f16x2 (RNE, init-time only)
__device__ __forceinline__ uint32_t pkh(float a, float b) {
  return (uint32_t)__half_as_ushort(__float2half(a)) |
         ((uint32_t)__half_as_ushort(__float2half(b)) << 16);
}
// pack two f32 -> f16x2 (RTZ, runtime, one v_cvt_pkrtz)
__device__ __forceinline__ uint32_t pkrtz(float a, float b) {
  auto p = __builtin_amdgcn_cvt_pkrtz(a, b);
  return __builtin_bit_cast(uint32_t, p);
}

__device__ __forceinline__ f32x4 mfma16(u32x4 a, u32x4 b, f32x4 c) {
  return __builtin_amdgcn_mfma_f32_16x16x32_f16(
      __builtin_bit_cast(f16x8, a), __builtin_bit_cast(f16x8, b), c, 0, 0, 0);
}

// MFMA batch-16 RNN: one wave handles 16 batch elements.
// D(units x batch) = A(weights 16x32, const regs) * B([x|h] 32x16) + C(bias).
// D col = lane&15 = batch = B col  ->  same lane owns the same batch before
// and after the matmul; h-exchange is 4 cvt_pk + 6 cross-lane ops + selects.
__global__ __launch_bounds__(BLOCK, 1) void rnn2_mfma(
    const float* __restrict__ x,
    const float* __restrict__ W_ih0, const float* __restrict__ W_hh0,
    const float* __restrict__ b_ih0, const float* __restrict__ b_hh0,
    const float* __restrict__ W_ih1, const float* __restrict__ W_hh1,
    const float* __restrict__ b_ih1, const float* __restrict__ b_hh1,
    const float* __restrict__ W_fc, const float* __restrict__ b_fc,
    float* __restrict__ out) {
  __shared__ __align__(16) float s_wfc[T * HP];
  for (int i = threadIdx.x; i < T * HP; i += BLOCK) {
    int t = i >> 4, u = i & 15;
    s_wfc[i] = (u < H) ? W_fc[t * H + u] : 0.0f;
  }
  __syncthreads();

  const int lane  = threadIdx.x;
  const int c     = lane & 15;        // batch column
  const int g     = lane >> 4;        // k-group / D-row group
  const int batch = blockIdx.x * 16 + c;
  const int u     = c;                // A-operand row = unit

  // ---- constant A fragments (weights) and C fragments (biases) ----
  // slot convention: reg r holds k = 8*g + 2r (lo), +1 (hi). Same convention
  // for A and B, so any true hardware k-permutation cancels.
  auto w0 = [&](int uu, int k) -> float {
    if (uu >= H) return 0.0f;
    if (k < 4)  return W_ih0[uu * F + k];
    if (k < 14) return W_hh0[uu * H + (k - 4)];
    return 0.0f;
  };
  auto w1 = [&](int uu, int k) -> float {
    if (uu >= H) return 0.0f;
    if (k < 10) return W_ih1[uu * H + k];
    if (k < 20) return W_hh1[uu * H + (k - 10)];
    return 0.0f;
  };
  u32x4 A0, A1;
#pragma unroll
  for (int r = 0; r < 4; ++r) {
    const int k0 = 8 * g + 2 * r;
    A0[r] = pkh(w0(u, k0), w0(u, k0 + 1));
    A1[r] = pkh(w1(u, k0), w1(u, k0 + 1));
  }
  f32x4 C0, C1;
#pragma unroll
  for (int i = 0; i < 4; ++i) {
    const int row = 4 * g + i;   // D row = unit index
    C0[i] = (row < H) ? (b_ih0[row] + b_hh0[row]) : 0.0f;
    C1[i] = (row < H) ? (b_ih1[row] + b_hh1[row]) : 0.0f;
  }

  const bool g0 = (g == 0), g1 = (g == 1), g2 = (g == 2);

  const float4* __restrict__ xrow =
      reinterpret_cast<const float4*>(x + (size_t)batch * (T * F));

  // packed h state: lane's own unit pair (4g,4g+1) in p0, (4g+2,4g+3) in p1.
  uint32_t h0p0 = 0, h0p1 = 0, h1p0 = 0, h1p1 = 0;
  // loop-carried exchanged copies (zero at t=0 since h=0)
  uint32_t e0_16a = 0, e0_16b = 0, e0_48a = 0;   // h0: sw16(p0), sw16(p1), x48(p0)
  uint32_t e1_16a = 0, e1_16b = 0, e1_48b = 0;   // h1: sw16(p0), sw16(p1), x48(p1)
  float acc = 0.0f;

  float4 xv = xrow[0];
#pragma unroll 1
  for (int t = 0; t < T; ++t) {
    float4 xn = xrow[(t + 1 < T) ? t + 1 : t];

    const uint32_t xpk0 = pkrtz(xv.x, xv.y);
    const uint32_t xpk1 = pkrtz(xv.z, xv.w);

    // ---- B0 = [x(k0..3) | h0(k4..13) | 0] ----
    u32x4 B0;
    B0[0] = g0 ? xpk0 : (g1 ? h0p0 : 0u);
    B0[1] = g0 ? xpk1 : (g1 ? h0p1 : 0u);
    B0[2] = g0 ? h0p0 : (g1 ? e0_48a : 0u);
    B0[3] = g0 ? h0p1 : 0u;

    f32x4 D0 = mfma16(A0, B0, C0);
    const float m0 = fast_tanh(D0[0]), m1 = fast_tanh(D0[1]);
    const float m2 = fast_tanh(D0[2]), m3 = fast_tanh(D0[3]);
    h0p0 = pkrtz(m0, m1);
    h0p1 = pkrtz(m2, m3);
    e0_16a = swz16(h0p0);
    e0_16b = swz16(h0p1);
    e0_48a = swz16((uint32_t)__shfl_xor((int)h0p0, 32));

    // ---- B1 = [h0(k0..9) | h1(k10..19) | 0]  (h1 = previous step) ----
    u32x4 B1;
    B1[0] = g0 ? h0p0   : (g1 ? e0_48a : (g2 ? e1_48b : 0u));
    B1[1] = g0 ? h0p1   : (g1 ? e1_16a : (g2 ? h1p0   : 0u));
    B1[2] = g0 ? e0_16a : (g1 ? e1_16b : 0u);
    B1[3] = g0 ? e0_16b : (g1 ? h1p0   : 0u);

    f32x4 D1 = mfma16(A1, B1, C1);
    const float n0 = fast_tanh(D1[0]), n1 = fast_tanh(D1[1]);
    const float n2 = fast_tanh(D1[2]), n3 = fast_tanh(D1[3]);

    // FC head: lane holds h1 units 4g..4g+3 of its batch
    const f32x4 wf = *reinterpret_cast<const f32x4*>(&s_wfc[t * HP + 4 * g]);
    acc = fmaf(n0, wf[0], acc);
    acc = fmaf(n1, wf[1], acc);
    acc = fmaf(n2, wf[2], acc);
    acc = fmaf(n3, wf[3], acc);

    h1p0 = pkrtz(n0, n1);
    h1p1 = pkrtz(n2, n3);
    e1_16a = swz16(h1p0);
    e1_16b = swz16(h1p1);
    e1_48b = swz16((uint32_t)__shfl_xor((int)h1p1, 32));

    xv = xn;
  }

  // reduce acc over the 4 g-groups (lanes c, c+16, c+32, c+48)
  acc += __shfl_xor(acc, 16);
  acc += __shfl_xor(acc, 32);
  if (lane < 16) out[batch] = fast_sigmoid(acc + b_fc[0]);
}

}  // namespace

extern "C" void kernel_launch(void* const* d_in, const int* in_sizes, int n_in,
                              void* d_out, int out_size, void* d_ws, size_t ws_size,
                              hipStream_t stream) {
  const float* x     = (const float*)d_in[0];
  const float* W_ih0 = (const float*)d_in[1];
  const float* W_hh0 = (const float*)d_in[2];
  const float* b_ih0 = (const float*)d_in[3];
  const float* b_hh0 = (const float*)d_in[4];
  const float* W_ih1 = (const float*)d_in[5];
  const float* W_hh1 = (const float*)d_in[6];
  const float* b_ih1 = (const float*)d_in[7];
  const float* b_hh1 = (const float*)d_in[8];
  const float* W_fc  = (const float*)d_in[9];
  const float* b_fc  = (const float*)d_in[10];
  float* out = (float*)d_out;

  dim3 grid(Bsz / 16), block(BLOCK);
  hipLaunchKernelGGL(rnn2_mfma, grid, block, 0, stream,
                     x, W_ih0, W_hh0, b_ih0, b_hh0,
                     W_ih1, W_hh1, b_ih1, b_hh1, W_fc, b_fc, out);
}